// Round 1
// baseline (484.313 us; speedup 1.0000x reference)
//
#include <hip/hip_runtime.h>
#include <stdint.h>

#define CIN 256
#define COUT 128
#define SDIM 512
#define NB 16

// x_pad geometry: [b][66 rows][66 cols][256 ci] bf16
#define XP_RSTRIDE 16896          // 66*256
#define XP_BSTRIDE 1115136        // 66*66*256
// A geometry: [b][512 m][2304 k] bf16
#define A_BSTRIDE (512*2304)

typedef __attribute__((ext_vector_type(8))) short short8;
typedef __attribute__((ext_vector_type(4))) float f32x4;

__device__ __forceinline__ float bf2f(unsigned short h) {
  union { unsigned int u; float f; } v; v.u = ((unsigned int)h) << 16; return v.f;
}
__device__ __forceinline__ unsigned short f2bf(float f) {
  union { float f; unsigned int u; } v; v.f = f;
  return (unsigned short)((v.u + 0x7fffu + ((v.u >> 16) & 1u)) >> 16);
}
__device__ __forceinline__ void gll16(const void* g, void* l) {
  __builtin_amdgcn_global_load_lds(
      (const __attribute__((address_space(1))) unsigned int*)g,
      (__attribute__((address_space(3))) unsigned int*)l, 16, 0, 0);
}

// ---------------- kernel 0: dtype detector ----------------
__global__ __launch_bounds__(256) void k_detect(
    const unsigned short* __restrict__ xr, int* __restrict__ flag) {
  __shared__ int red[4];
  int t = threadIdx.x, cnt = 0;
  for (int i = t; i < 8192; i += 256) {
    int e = (xr[2*i] >> 7) & 0xff;
    cnt += (e > 90 && e < 145) ? 1 : 0;
  }
  #pragma unroll
  for (int off = 32; off > 0; off >>= 1) cnt += __shfl_down(cnt, off);
  if ((t & 63) == 0) red[t >> 6] = cnt;
  __syncthreads();
  if (t == 0) *flag = (red[0] + red[1] + red[2] + red[3] < 5000) ? 1 : 0;  // 1 = f32
}

// ---------------- kernel 1: s = style @ mod_w^T + mod_b ----------------
__global__ __launch_bounds__(256) void k_style(
    const void* __restrict__ style_v, const void* __restrict__ mod_w_v,
    const void* __restrict__ mod_b_v, const int* __restrict__ flag,
    float* __restrict__ s_out) {                // [16][256] f32
  __shared__ float st[SDIM];
  int b = blockIdx.x, t = threadIdx.x;
  int isf = *flag;
  float acc;
  if (!isf) {
    const unsigned short* style = (const unsigned short*)style_v;
    const unsigned short* mod_w = (const unsigned short*)mod_w_v;
    const unsigned short* mod_b = (const unsigned short*)mod_b_v;
    st[t]       = bf2f(style[b*SDIM + t]);
    st[t + 256] = bf2f(style[b*SDIM + t + 256]);
    __syncthreads();
    const uint4* wr = (const uint4*)(mod_w + (size_t)t*SDIM);
    acc = bf2f(mod_b[t]);
    #pragma unroll 4
    for (int s8 = 0; s8 < SDIM/8; ++s8) {
      uint4 p = wr[s8];
      int sb = s8*8;
      acc += bf2f((unsigned short)(p.x & 0xffff))*st[sb]
           + bf2f((unsigned short)(p.x >> 16))   *st[sb+1]
           + bf2f((unsigned short)(p.y & 0xffff))*st[sb+2]
           + bf2f((unsigned short)(p.y >> 16))   *st[sb+3]
           + bf2f((unsigned short)(p.z & 0xffff))*st[sb+4]
           + bf2f((unsigned short)(p.z >> 16))   *st[sb+5]
           + bf2f((unsigned short)(p.w & 0xffff))*st[sb+6]
           + bf2f((unsigned short)(p.w >> 16))   *st[sb+7];
    }
  } else {
    const float* style = (const float*)style_v;
    const float* mod_w = (const float*)mod_w_v;
    const float* mod_b = (const float*)mod_b_v;
    st[t]       = style[b*SDIM + t];
    st[t + 256] = style[b*SDIM + t + 256];
    __syncthreads();
    const float4* wr = (const float4*)(mod_w + (size_t)t*SDIM);
    acc = mod_b[t];
    #pragma unroll 4
    for (int s4 = 0; s4 < SDIM/4; ++s4) {
      float4 p = wr[s4];
      int sb = s4*4;
      acc += p.x*st[sb] + p.y*st[sb+1] + p.z*st[sb+2] + p.w*st[sb+3];
    }
  }
  s_out[b*CIN + t] = acc;
}

// ---------------- kernel 2: modulate+demod+blur-fold -> A[b][m][k] ----------------
// m = py*256 + co*2 + px ; k = tap*256 + ci, tap = (dh+1)*3+(dw+1)
__global__ __launch_bounds__(256) void k_weights(
    const void* __restrict__ weight_v,          // [128][256][3][3]
    const float* __restrict__ s_in,             // [16][256]
    const int* __restrict__ flag,
    unsigned short* __restrict__ Aw) {
  int co = blockIdx.x, b = blockIdx.y, ci = threadIdx.x;
  int isf = *flag;
  float sm = 0.0208333333333333f * s_in[b*CIN + ci];   // 1/48 = 1/sqrt(2304)
  float w9[9]; float ss = 0.f;
  if (!isf) {
    const unsigned short* wp = (const unsigned short*)weight_v + ((size_t)co*CIN + ci)*9;
    #pragma unroll
    for (int k = 0; k < 9; ++k) { float v = bf2f(wp[k]) * sm; w9[k] = v; ss += v*v; }
  } else {
    const float* wp = (const float*)weight_v + ((size_t)co*CIN + ci)*9;
    #pragma unroll
    for (int k = 0; k < 9; ++k) { float v = wp[k] * sm; w9[k] = v; ss += v*v; }
  }
  #pragma unroll
  for (int off = 32; off > 0; off >>= 1) ss += __shfl_down(ss, off);
  __shared__ float red[4];
  if ((ci & 63) == 0) red[ci >> 6] = ss;
  __syncthreads();
  float demod = rsqrtf(red[0] + red[1] + red[2] + red[3] + 1e-8f);
  #pragma unroll
  for (int k = 0; k < 9; ++k) w9[k] *= demod;
  const float F[4] = {0.25f, 0.75f, 0.75f, 0.25f};   // [1,3,3,1]/4 (x4 up-gain folded)
  float C6[6][6];
  #pragma unroll
  for (int ty = 0; ty < 6; ++ty) {
    #pragma unroll
    for (int tx = 0; tx < 6; ++tx) {
      float acc = 0.f;
      #pragma unroll
      for (int ay = 0; ay < 3; ++ay) {
        int fy = ay - ty + 3;
        if (fy < 0 || fy > 3) continue;
        float ra = 0.f;
        #pragma unroll
        for (int ax = 0; ax < 3; ++ax) {
          int fx = ax - tx + 3;
          if (fx < 0 || fx > 3) continue;
          ra += w9[ay*3 + ax] * F[fx];
        }
        acc += ra * F[fy];
      }
      C6[ty][tx] = acc;
    }
  }
  unsigned short* Ab = Aw + (size_t)b*A_BSTRIDE;
  #pragma unroll
  for (int py = 0; py < 2; ++py) {
    #pragma unroll
    for (int px = 0; px < 2; ++px) {
      unsigned short* Am = Ab + (size_t)(py*256 + co*2 + px)*2304 + ci;
      #pragma unroll
      for (int dh = -1; dh <= 1; ++dh) {
        #pragma unroll
        for (int dw = -1; dw <= 1; ++dw) {
          int tap = (dh+1)*3 + (dw+1);
          Am[tap*256] = f2bf(C6[py - 2*dh + 2][px - 2*dw + 2]);
        }
      }
    }
  }
}

// ---------------- kernel 3: x -> x_pad[b][r+1][c+1][ci] bf16, zero halo ----------------
// v2: dword-packed ci-pairs through LDS; conflict-free (2-way) both directions.
__global__ __launch_bounds__(256) void k_transpose(
    const void* __restrict__ x_v,   // [16][256][64][64] bf16 or f32
    const int* __restrict__ flag,
    unsigned short* __restrict__ xp) {
  int r_out = blockIdx.x, b = blockIdx.y, t = threadIdx.x;
  unsigned short* rp = xp + (size_t)b*XP_BSTRIDE + (size_t)r_out*XP_RSTRIDE;
  int r_in = r_out - 1;
  if (r_in < 0 || r_in >= 64) {          // border rows: all zero
    uint4 z = make_uint4(0,0,0,0);
    #pragma unroll
    for (int i = 0; i < 9; ++i) {
      int idx = i*256 + t;
      if (idx < 2112) ((uint4*)rp)[idx] = z;   // 16896 u16 = 2112 uint4
    }
    return;
  }
  if (t < 64) {                           // border cols 0 and 65: zero
    uint4 z = make_uint4(0,0,0,0);
    int col = (t < 32) ? 0 : 65;
    ((uint4*)(rp + col*256))[t & 31] = z;
  }
  int isf = *flag;
  __shared__ unsigned int lds32[64*33];   // [c 64][ci-pair 32], stride 33 dwords
  int tci = t >> 3;                       // ci-pair index 0..31
  int tc8 = t & 7;                        // c-octet 0..7
  int cS  = t >> 2;                       // store-side c 0..63
  int jg  = t & 3;                        // store-side ci chunk (16 ci)
  for (int g4 = 0; g4 < 4; ++g4) {
    int ci0 = g4 * 64;
    int ci = ci0 + tci*2;
    size_t base = (((size_t)b*CIN + ci)*64 + r_in)*64 + tc8*8;
    unsigned int v[8];
    if (isf) {
      const float* s0 = (const float*)x_v + base;
      const float* s1 = s0 + 4096;
      float4 a0 = ((const float4*)s0)[0], a1 = ((const float4*)s0)[1];
      float4 b0 = ((const float4*)s1)[0], b1 = ((const float4*)s1)[1];
      v[0] = f2bf(a0.x) | ((unsigned int)f2bf(b0.x) << 16);
      v[1] = f2bf(a0.y) | ((unsigned int)f2bf(b0.y) << 16);
      v[2] = f2bf(a0.z) | ((unsigned int)f2bf(b0.z) << 16);
      v[3] = f2bf(a0.w) | ((unsigned int)f2bf(b0.w) << 16);
      v[4] = f2bf(a1.x) | ((unsigned int)f2bf(b1.x) << 16);
      v[5] = f2bf(a1.y) | ((unsigned int)f2bf(b1.y) << 16);
      v[6] = f2bf(a1.z) | ((unsigned int)f2bf(b1.z) << 16);
      v[7] = f2bf(a1.w) | ((unsigned int)f2bf(b1.w) << 16);
    } else {
      const unsigned short* s0 = (const unsigned short*)x_v + base;
      const unsigned short* s1 = s0 + 4096;
      union { uint4 q; unsigned short h[8]; } u0, u1;
      u0.q = *(const uint4*)s0; u1.q = *(const uint4*)s1;
      #pragma unroll
      for (int j = 0; j < 8; ++j)
        v[j] = (unsigned int)u0.h[j] | ((unsigned int)u1.h[j] << 16);
    }
    if (g4) __syncthreads();
    #pragma unroll
    for (int j = 0; j < 8; ++j)
      lds32[(tc8*8 + j)*33 + tci] = v[j];
    __syncthreads();
    union { unsigned int o[8]; uint4 q[2]; } ob;
    #pragma unroll
    for (int w = 0; w < 8; ++w)
      ob.o[w] = lds32[cS*33 + jg*8 + w];
    uint4* dst = (uint4*)(rp + (size_t)(cS+1)*256 + ci0 + jg*16);
    dst[0] = ob.q[0];
    dst[1] = ob.q[1];
  }
}

// ---------------- kernel 4: implicit-GEMM subpixel conv ----------------
// v3: 128m x 256n block tile (4 waves, 64x128 per wave, acc[4][8]),
// double-buffered LDS with prefetch-before-compute (single barrier/stage),
// XOR-swizzled k-chunk staging retained (2-way aliasing = free).
__global__ __launch_bounds__(256) void k_gemm(
    const unsigned short* __restrict__ Aw,
    const unsigned short* __restrict__ xp,
    const int* __restrict__ flag,
    void* __restrict__ out) {
  __shared__ __align__(16) unsigned short As[2][128*32];   // 16 KB
  __shared__ __align__(16) unsigned short Bs[2][256*32];   // 32 KB
  int g = blockIdx.x;                  // 1024 blocks
  int b  = ((g & 7) << 1) | ((g >> 3) & 1);   // 2 batch samples per XCD
  int mt = (g >> 4) & 3;               // 128-row m tile
  int nt = g >> 6;                     // 0..15, 4 y-rows each
  int yy0 = nt << 2;
  int t = threadIdx.x;
  int wave = t >> 6, lane = t & 63;
  int row = t >> 2, part = t & 3;
  int isf = *flag;

  // source-permuted staging: physical slot (row, part) holds k-chunk part^((row>>2)&3)
  int partS = part ^ ((row >> 2) & 3);
  int dstOff = row*32 + part*8;        // shorts; = thread-linear 16B slots
  const unsigned short* gA0 = Aw + (size_t)b*A_BSTRIDE + (size_t)(mt*128 + row)*2304 + partS*8;
  const unsigned short* gA1 = gA0 + (size_t)64*2304;
  const unsigned short* gB0 = xp + (size_t)b*XP_BSTRIDE + (size_t)(yy0 + 1)*XP_RSTRIDE
                              + (size_t)(row + 1)*256 + partS*8;

  f32x4 acc[4][8];
  #pragma unroll
  for (int i = 0; i < 4; ++i)
    #pragma unroll
    for (int j = 0; j < 8; ++j)
      acc[i][j] = (f32x4){0.f, 0.f, 0.f, 0.f};

  int l15 = lane & 15, q = lane >> 4;
  int qs = q ^ ((l15 >> 2) & 3);       // frag-read swizzle (invariant across frags)
  int wm = wave >> 1, wn = wave & 1;   // 2m x 2n wave grid
  int rAoff = (wm*64 + l15)*32 + qs*8;
  int rBoff = (wn*128 + l15)*32 + qs*8;

  unsigned short* sAc = (unsigned short*)As[0];
  unsigned short* sAn = (unsigned short*)As[1];
  unsigned short* sBc = (unsigned short*)Bs[0];
  unsigned short* sBn = (unsigned short*)Bs[1];

  // stage s: tap = s>>3 (9 taps), kk = s&7 (8 x 32-k chunks)
  #define STAGE(SA, SB, S) { \
    int tap_ = (S) >> 3; int kk_ = (S) & 7; \
    int dh_ = (tap_ >= 6) ? 1 : ((tap_ >= 3) ? 0 : -1); \
    int dwx_ = tap_ - (dh_ + 1)*3 - 1; \
    int ao_ = tap_*256 + kk_*32; \
    int bo_ = dh_*XP_RSTRIDE + dwx_*256 + kk_*32; \
    unsigned short* dA_ = (SA) + dstOff; \
    unsigned short* dB_ = (SB) + dstOff; \
    gll16(gA0 + ao_, dA_); \
    gll16(gA1 + ao_, dA_ + 2048); \
    gll16(gB0 + bo_, dB_); \
    gll16(gB0 + bo_ + XP_RSTRIDE,   dB_ + 2048); \
    gll16(gB0 + bo_ + 2*XP_RSTRIDE, dB_ + 4096); \
    gll16(gB0 + bo_ + 3*XP_RSTRIDE, dB_ + 6144); \
  }

  STAGE(sAc, sBc, 0);
  __syncthreads();

  for (int s = 0; s < 72; ++s) {
    if (s < 71) STAGE(sAn, sBn, s + 1);     // prefetch next chunk (other buffer)
    const unsigned short* rA = sAc + rAoff;
    const unsigned short* rB = sBc + rBoff;
    short8 af[4];
    #pragma unroll
    for (int i = 0; i < 4; ++i)
      af[i] = *(const short8*)(rA + i*512);
    #pragma unroll
    for (int j = 0; j < 8; ++j) {
      short8 bv = *(const short8*)(rB + j*512);
      #pragma unroll
      for (int i = 0; i < 4; ++i)
        acc[i][j] = __builtin_amdgcn_mfma_f32_16x16x32_bf16(af[i], bv, acc[i][j], 0, 0, 0);
    }
    __syncthreads();                        // drains vmcnt(0): prefetch landed
    unsigned short* tp_;
    tp_ = sAc; sAc = sAn; sAn = tp_;
    tp_ = sBc; sBc = sBn; sBn = tp_;
  }
  #undef STAGE

  // epilogue: D row = q*4+reg (m), col = l15 (n); m = py*256 + co*2 + px
  int py = mt >> 1;
  if (!isf) {
    unsigned int* outp = (unsigned int*)out;
    #pragma unroll
    for (int i = 0; i < 4; ++i) {
      #pragma unroll
      for (int rr = 0; rr < 2; ++rr) {
        int co = ((mt & 1) << 6) + (wm << 5) + i*8 + q*2 + rr;
        #pragma unroll
        for (int j = 0; j < 8; ++j) {
          int ryl = (wn << 1) + (j >> 2);
          int y = ((yy0 + ryl) << 1) + py;
          int x = ((j & 3) << 4) + l15;
          size_t oidx = (((size_t)b*COUT + co)*128 + y)*64 + x;
          unsigned int pk = (unsigned int)f2bf(acc[i][j][rr*2])
                          | ((unsigned int)f2bf(acc[i][j][rr*2 + 1]) << 16);
          outp[oidx] = pk;
        }
      }
    }
  } else {
    float2* outp = (float2*)out;
    #pragma unroll
    for (int i = 0; i < 4; ++i) {
      #pragma unroll
      for (int rr = 0; rr < 2; ++rr) {
        int co = ((mt & 1) << 6) + (wm << 5) + i*8 + q*2 + rr;
        #pragma unroll
        for (int j = 0; j < 8; ++j) {
          int ryl = (wn << 1) + (j >> 2);
          int y = ((yy0 + ryl) << 1) + py;
          int x = ((j & 3) << 4) + l15;
          size_t oidx = (((size_t)b*COUT + co)*128 + y)*64 + x;
          outp[oidx] = make_float2(acc[i][j][rr*2], acc[i][j][rr*2 + 1]);
        }
      }
    }
  }
}

extern "C" void kernel_launch(void* const* d_in, const int* in_sizes, int n_in,
                              void* d_out, int out_size, void* d_ws, size_t ws_size,
                              hipStream_t stream) {
  const void* x      = d_in[0];
  const void* style  = d_in[1];
  const void* weight = d_in[2];
  const void* mod_w  = d_in[3];
  const void* mod_b  = d_in[4];
  char* ws = (char*)d_ws;
  int* flag           = (int*)ws;                                     // 4 B
  float* s_buf        = (float*)(ws + 1024);                          // 16 KB
  unsigned short* Aw  = (unsigned short*)(ws + 32768);                // 37,748,736 B
  unsigned short* xpd = (unsigned short*)(ws + 32768 + 37748736);     // 35,684,352 B

  k_detect   <<<1, 256, 0, stream>>>((const unsigned short*)x, flag);
  k_style    <<<NB, 256, 0, stream>>>(style, mod_w, mod_b, flag, s_buf);
  k_weights  <<<dim3(COUT, NB), 256, 0, stream>>>(weight, s_buf, flag, Aw);
  k_transpose<<<dim3(66, NB), 256, 0, stream>>>(x, flag, xpd);
  k_gemm     <<<1024, 256, 0, stream>>>(Aw, xpd, flag, d_out);
}

// Round 3
// 431.095 us; speedup vs baseline: 1.1234x; 1.1234x over previous
//
#include <hip/hip_runtime.h>
#include <stdint.h>

#define CIN 256
#define COUT 128
#define SDIM 512
#define NB 16

// x_pad geometry: [b][66 rows][66 cols][256 ci] bf16
#define XP_RSTRIDE 16896          // 66*256
#define XP_BSTRIDE 1115136        // 66*66*256
// A geometry: [b][512 m][2304 k] bf16
#define A_BSTRIDE (512*2304)

typedef __attribute__((ext_vector_type(8))) short short8;
typedef __attribute__((ext_vector_type(4))) float f32x4;

__device__ __forceinline__ float bf2f(unsigned short h) {
  union { unsigned int u; float f; } v; v.u = ((unsigned int)h) << 16; return v.f;
}
__device__ __forceinline__ unsigned short f2bf(float f) {
  union { float f; unsigned int u; } v; v.f = f;
  return (unsigned short)((v.u + 0x7fffu + ((v.u >> 16) & 1u)) >> 16);
}
__device__ __forceinline__ void gll16(const void* g, void* l) {
  __builtin_amdgcn_global_load_lds(
      (const __attribute__((address_space(1))) unsigned int*)g,
      (__attribute__((address_space(3))) unsigned int*)l, 16, 0, 0);
}

// ---------------- kernel 0: dtype detector ----------------
__global__ __launch_bounds__(256) void k_detect(
    const unsigned short* __restrict__ xr, int* __restrict__ flag) {
  __shared__ int red[4];
  int t = threadIdx.x, cnt = 0;
  for (int i = t; i < 8192; i += 256) {
    int e = (xr[2*i] >> 7) & 0xff;
    cnt += (e > 90 && e < 145) ? 1 : 0;
  }
  #pragma unroll
  for (int off = 32; off > 0; off >>= 1) cnt += __shfl_down(cnt, off);
  if ((t & 63) == 0) red[t >> 6] = cnt;
  __syncthreads();
  if (t == 0) *flag = (red[0] + red[1] + red[2] + red[3] < 5000) ? 1 : 0;  // 1 = f32
}

// ---------------- kernel 1: s = style @ mod_w^T + mod_b ----------------
__global__ __launch_bounds__(256) void k_style(
    const void* __restrict__ style_v, const void* __restrict__ mod_w_v,
    const void* __restrict__ mod_b_v, const int* __restrict__ flag,
    float* __restrict__ s_out) {                // [16][256] f32
  __shared__ float st[SDIM];
  int b = blockIdx.x, t = threadIdx.x;
  int isf = *flag;
  float acc;
  if (!isf) {
    const unsigned short* style = (const unsigned short*)style_v;
    const unsigned short* mod_w = (const unsigned short*)mod_w_v;
    const unsigned short* mod_b = (const unsigned short*)mod_b_v;
    st[t]       = bf2f(style[b*SDIM + t]);
    st[t + 256] = bf2f(style[b*SDIM + t + 256]);
    __syncthreads();
    const uint4* wr = (const uint4*)(mod_w + (size_t)t*SDIM);
    acc = bf2f(mod_b[t]);
    #pragma unroll 4
    for (int s8 = 0; s8 < SDIM/8; ++s8) {
      uint4 p = wr[s8];
      int sb = s8*8;
      acc += bf2f((unsigned short)(p.x & 0xffff))*st[sb]
           + bf2f((unsigned short)(p.x >> 16))   *st[sb+1]
           + bf2f((unsigned short)(p.y & 0xffff))*st[sb+2]
           + bf2f((unsigned short)(p.y >> 16))   *st[sb+3]
           + bf2f((unsigned short)(p.z & 0xffff))*st[sb+4]
           + bf2f((unsigned short)(p.z >> 16))   *st[sb+5]
           + bf2f((unsigned short)(p.w & 0xffff))*st[sb+6]
           + bf2f((unsigned short)(p.w >> 16))   *st[sb+7];
    }
  } else {
    const float* style = (const float*)style_v;
    const float* mod_w = (const float*)mod_w_v;
    const float* mod_b = (const float*)mod_b_v;
    st[t]       = style[b*SDIM + t];
    st[t + 256] = style[b*SDIM + t + 256];
    __syncthreads();
    const float4* wr = (const float4*)(mod_w + (size_t)t*SDIM);
    acc = mod_b[t];
    #pragma unroll 4
    for (int s4 = 0; s4 < SDIM/4; ++s4) {
      float4 p = wr[s4];
      int sb = s4*4;
      acc += p.x*st[sb] + p.y*st[sb+1] + p.z*st[sb+2] + p.w*st[sb+3];
    }
  }
  s_out[b*CIN + t] = acc;
}

// ---------------- kernel 2: modulate+demod+blur-fold -> A[b][m][k] ----------------
// m = py*256 + co*2 + px ; k = tap*256 + ci, tap = (dh+1)*3+(dw+1)
__global__ __launch_bounds__(256) void k_weights(
    const void* __restrict__ weight_v,          // [128][256][3][3]
    const float* __restrict__ s_in,             // [16][256]
    const int* __restrict__ flag,
    unsigned short* __restrict__ Aw) {
  int co = blockIdx.x, b = blockIdx.y, ci = threadIdx.x;
  int isf = *flag;
  float sm = 0.0208333333333333f * s_in[b*CIN + ci];   // 1/48 = 1/sqrt(2304)
  float w9[9]; float ss = 0.f;
  if (!isf) {
    const unsigned short* wp = (const unsigned short*)weight_v + ((size_t)co*CIN + ci)*9;
    #pragma unroll
    for (int k = 0; k < 9; ++k) { float v = bf2f(wp[k]) * sm; w9[k] = v; ss += v*v; }
  } else {
    const float* wp = (const float*)weight_v + ((size_t)co*CIN + ci)*9;
    #pragma unroll
    for (int k = 0; k < 9; ++k) { float v = wp[k] * sm; w9[k] = v; ss += v*v; }
  }
  #pragma unroll
  for (int off = 32; off > 0; off >>= 1) ss += __shfl_down(ss, off);
  __shared__ float red[4];
  if ((ci & 63) == 0) red[ci >> 6] = ss;
  __syncthreads();
  float demod = rsqrtf(red[0] + red[1] + red[2] + red[3] + 1e-8f);
  #pragma unroll
  for (int k = 0; k < 9; ++k) w9[k] *= demod;
  const float F[4] = {0.25f, 0.75f, 0.75f, 0.25f};   // [1,3,3,1]/4 (x4 up-gain folded)
  float C6[6][6];
  #pragma unroll
  for (int ty = 0; ty < 6; ++ty) {
    #pragma unroll
    for (int tx = 0; tx < 6; ++tx) {
      float acc = 0.f;
      #pragma unroll
      for (int ay = 0; ay < 3; ++ay) {
        int fy = ay - ty + 3;
        if (fy < 0 || fy > 3) continue;
        float ra = 0.f;
        #pragma unroll
        for (int ax = 0; ax < 3; ++ax) {
          int fx = ax - tx + 3;
          if (fx < 0 || fx > 3) continue;
          ra += w9[ay*3 + ax] * F[fx];
        }
        acc += ra * F[fy];
      }
      C6[ty][tx] = acc;
    }
  }
  unsigned short* Ab = Aw + (size_t)b*A_BSTRIDE;
  #pragma unroll
  for (int py = 0; py < 2; ++py) {
    #pragma unroll
    for (int px = 0; px < 2; ++px) {
      unsigned short* Am = Ab + (size_t)(py*256 + co*2 + px)*2304 + ci;
      #pragma unroll
      for (int dh = -1; dh <= 1; ++dh) {
        #pragma unroll
        for (int dw = -1; dw <= 1; ++dw) {
          int tap = (dh+1)*3 + (dw+1);
          Am[tap*256] = f2bf(C6[py - 2*dh + 2][px - 2*dw + 2]);
        }
      }
    }
  }
}

// ---------------- kernel 3: x -> x_pad[b][r+1][c+1][ci] bf16, zero halo ----------------
// v2: dword-packed ci-pairs through LDS; conflict-free (2-way) both directions.
__global__ __launch_bounds__(256) void k_transpose(
    const void* __restrict__ x_v,   // [16][256][64][64] bf16 or f32
    const int* __restrict__ flag,
    unsigned short* __restrict__ xp) {
  int r_out = blockIdx.x, b = blockIdx.y, t = threadIdx.x;
  unsigned short* rp = xp + (size_t)b*XP_BSTRIDE + (size_t)r_out*XP_RSTRIDE;
  int r_in = r_out - 1;
  if (r_in < 0 || r_in >= 64) {          // border rows: all zero
    uint4 z = make_uint4(0,0,0,0);
    #pragma unroll
    for (int i = 0; i < 9; ++i) {
      int idx = i*256 + t;
      if (idx < 2112) ((uint4*)rp)[idx] = z;   // 16896 u16 = 2112 uint4
    }
    return;
  }
  if (t < 64) {                           // border cols 0 and 65: zero
    uint4 z = make_uint4(0,0,0,0);
    int col = (t < 32) ? 0 : 65;
    ((uint4*)(rp + col*256))[t & 31] = z;
  }
  int isf = *flag;
  __shared__ unsigned int lds32[64*33];   // [c 64][ci-pair 32], stride 33 dwords
  int tci = t >> 3;                       // ci-pair index 0..31
  int tc8 = t & 7;                        // c-octet 0..7
  int cS  = t >> 2;                       // store-side c 0..63
  int jg  = t & 3;                        // store-side ci chunk (16 ci)
  for (int g4 = 0; g4 < 4; ++g4) {
    int ci0 = g4 * 64;
    int ci = ci0 + tci*2;
    size_t base = (((size_t)b*CIN + ci)*64 + r_in)*64 + tc8*8;
    unsigned int v[8];
    if (isf) {
      const float* s0 = (const float*)x_v + base;
      const float* s1 = s0 + 4096;
      float4 a0 = ((const float4*)s0)[0], a1 = ((const float4*)s0)[1];
      float4 b0 = ((const float4*)s1)[0], b1 = ((const float4*)s1)[1];
      v[0] = f2bf(a0.x) | ((unsigned int)f2bf(b0.x) << 16);
      v[1] = f2bf(a0.y) | ((unsigned int)f2bf(b0.y) << 16);
      v[2] = f2bf(a0.z) | ((unsigned int)f2bf(b0.z) << 16);
      v[3] = f2bf(a0.w) | ((unsigned int)f2bf(b0.w) << 16);
      v[4] = f2bf(a1.x) | ((unsigned int)f2bf(b1.x) << 16);
      v[5] = f2bf(a1.y) | ((unsigned int)f2bf(b1.y) << 16);
      v[6] = f2bf(a1.z) | ((unsigned int)f2bf(b1.z) << 16);
      v[7] = f2bf(a1.w) | ((unsigned int)f2bf(b1.w) << 16);
    } else {
      const unsigned short* s0 = (const unsigned short*)x_v + base;
      const unsigned short* s1 = s0 + 4096;
      union { uint4 q; unsigned short h[8]; } u0, u1;
      u0.q = *(const uint4*)s0; u1.q = *(const uint4*)s1;
      #pragma unroll
      for (int j = 0; j < 8; ++j)
        v[j] = (unsigned int)u0.h[j] | ((unsigned int)u1.h[j] << 16);
    }
    if (g4) __syncthreads();
    #pragma unroll
    for (int j = 0; j < 8; ++j)
      lds32[(tc8*8 + j)*33 + tci] = v[j];
    __syncthreads();
    union { unsigned int o[8]; uint4 q[2]; } ob;
    #pragma unroll
    for (int w = 0; w < 8; ++w)
      ob.o[w] = lds32[cS*33 + jg*8 + w];
    uint4* dst = (uint4*)(rp + (size_t)(cS+1)*256 + ci0 + jg*16);
    dst[0] = ob.q[0];
    dst[1] = ob.q[1];
  }
}

// ---------------- kernel 4: implicit-GEMM subpixel conv ----------------
// v4: back to 128x128 tile / 64x64 per wave (v2 geometry, proven fastest for
// shallow pipelines), but with a TRUE double-buffer: compile-time buffer
// indices (As[0]/As[1] disjoint constant ranges -> AA can prove prefetch
// doesn't alias compute buffer -> no early vmcnt drain), prefetch issued
// before compute, single barrier per 32-k step AFTER compute.
// Tap-outer / kk-unrolled retained so all stage offsets fold to immediates.
__global__ __launch_bounds__(256) void k_gemm(
    const unsigned short* __restrict__ Aw,
    const unsigned short* __restrict__ xp,
    const int* __restrict__ flag,
    void* __restrict__ out) {
  __shared__ __align__(16) unsigned short As[2][128*32];   // 2 x 8 KB
  __shared__ __align__(16) unsigned short Bs[2][128*32];   // 2 x 8 KB
  int g = blockIdx.x;                  // 2048 blocks
  int b  = ((g & 7) << 1) | ((g >> 3) & 1);   // 2 batch samples per XCD
  int mt = (g >> 4) & 3;
  int nt = g >> 6;                 // 0..31
  int yy0 = nt << 1;
  int t = threadIdx.x;
  int wave = t >> 6, lane = t & 63;
  int row = t >> 2, part = t & 3;
  int isf = *flag;

  // source-permuted staging: physical slot (row, part) holds k-chunk part^((row>>2)&3)
  int partS = part ^ ((row >> 2) & 3);
  int dstOff = row*32 + part*8;        // thread-linear 16B slots (matches gll16 HW layout)
  const unsigned short* pA0 = Aw + (size_t)b*A_BSTRIDE + (size_t)(mt*128 + row)*2304 + partS*8;
  const unsigned short* pA1 = pA0 + (size_t)64*2304;
  const unsigned short* pB0 = xp + (size_t)b*XP_BSTRIDE + (size_t)(yy0 + 1)*XP_RSTRIDE
                              + (size_t)(row + 1)*256 + partS*8;

  f32x4 acc[4][4];
  #pragma unroll
  for (int i = 0; i < 4; ++i)
    #pragma unroll
    for (int j = 0; j < 4; ++j)
      acc[i][j] = (f32x4){0.f, 0.f, 0.f, 0.f};

  int mb = (wave >> 1) << 6;   // wave m-base
  int nb = (wave & 1) << 6;    // wave n-base
  int l15 = lane & 15, q = lane >> 4;
  int qs = q ^ ((l15 >> 2) & 3);          // frag-read swizzle (conflict-free)

  #define STAGE(BI, A0, A1, B0, KK) { \
    gll16((A0) + (KK)*32, &As[BI][dstOff]); \
    gll16((A1) + (KK)*32, &As[BI][dstOff + 2048]); \
    gll16((B0) + (KK)*32, &Bs[BI][dstOff]); \
    gll16((B0) + (KK)*32 + XP_RSTRIDE, &Bs[BI][dstOff + 2048]); \
  }

  #define COMPUTE(BI) { \
    short8 af[4], bv[4]; \
    _Pragma("unroll") \
    for (int i_ = 0; i_ < 4; ++i_) \
      af[i_] = *(const short8*)&As[BI][(mb + i_*16 + l15)*32 + qs*8]; \
    _Pragma("unroll") \
    for (int j_ = 0; j_ < 4; ++j_) \
      bv[j_] = *(const short8*)&Bs[BI][(nb + j_*16 + l15)*32 + qs*8]; \
    _Pragma("unroll") \
    for (int i_ = 0; i_ < 4; ++i_) \
      _Pragma("unroll") \
      for (int j_ = 0; j_ < 4; ++j_) \
        acc[i_][j_] = __builtin_amdgcn_mfma_f32_16x16x32_bf16(af[i_], bv[j_], acc[i_][j_], 0, 0, 0); \
  }

  // prologue: tap 0 (dh=-1, dwx=-1), chunk 0 -> buf0
  STAGE(0, pA0, pA1, pB0 - XP_RSTRIDE - 256, 0);
  __syncthreads();

  for (int tap = 0; tap < 9; ++tap) {
    int dh  = (tap >= 6) ? 1 : ((tap >= 3) ? 0 : -1);
    int dwx = tap - (dh + 1)*3 - 1;
    const unsigned short* a0 = pA0 + tap*256;
    const unsigned short* a1 = pA1 + tap*256;
    const unsigned short* b0 = pB0 + dh*XP_RSTRIDE + dwx*256;
    // next-tap B base (A just advances +256; computed inline)
    int tap1 = tap + 1;
    int dh1  = (tap1 >= 6) ? 1 : ((tap1 >= 3) ? 0 : -1);
    int dwx1 = tap1 - (dh1 + 1)*3 - 1;
    const unsigned short* nb0 = pB0 + dh1*XP_RSTRIDE + dwx1*256;
    #pragma unroll
    for (int kk = 0; kk < 8; kk += 2) {
      // even step: prefetch kk+1 -> buf1, compute buf0 (chunk kk)
      STAGE(1, a0, a1, b0, kk + 1);
      COMPUTE(0);
      __syncthreads();                     // vmcnt(0) lands AFTER compute
      // odd step: prefetch kk+2 (or next tap chunk 0) -> buf0, compute buf1
      if (kk < 6) {
        STAGE(0, a0, a1, b0, kk + 2);
      } else if (tap < 8) {
        STAGE(0, a0 + 256, a1 + 256, nb0, 0);
      }
      COMPUTE(1);
      if (!(tap == 8 && kk == 6)) __syncthreads();
    }
  }
  #undef STAGE
  #undef COMPUTE

  // epilogue: D row m = q*4+reg; m = py*256 + co*2 + px
  int py = mt >> 1;
  int ry = wave & 1;
  int y = ((yy0 + ry) << 1) + py;
  int cobase = ((mt & 1) << 6) + ((wave >> 1) << 5);
  #pragma unroll
  for (int i = 0; i < 4; ++i) {
    #pragma unroll
    for (int rr = 0; rr < 2; ++rr) {
      int co = cobase + i*8 + q*2 + rr;
      size_t obase = (((size_t)b*COUT + co)*128 + y)*64;
      if (!isf) {
        unsigned int* outp = (unsigned int*)out;
        #pragma unroll
        for (int j = 0; j < 4; ++j) {
          unsigned int pk = (unsigned int)f2bf(acc[i][j][rr*2])
                          | ((unsigned int)f2bf(acc[i][j][rr*2 + 1]) << 16);
          outp[obase + j*16 + l15] = pk;
        }
      } else {
        float2* outp = (float2*)out;
        #pragma unroll
        for (int j = 0; j < 4; ++j)
          outp[obase + j*16 + l15] = make_float2(acc[i][j][rr*2], acc[i][j][rr*2 + 1]);
      }
    }
  }
}

extern "C" void kernel_launch(void* const* d_in, const int* in_sizes, int n_in,
                              void* d_out, int out_size, void* d_ws, size_t ws_size,
                              hipStream_t stream) {
  const void* x      = d_in[0];
  const void* style  = d_in[1];
  const void* weight = d_in[2];
  const void* mod_w  = d_in[3];
  const void* mod_b  = d_in[4];
  char* ws = (char*)d_ws;
  int* flag           = (int*)ws;                                     // 4 B
  float* s_buf        = (float*)(ws + 1024);                          // 16 KB
  unsigned short* Aw  = (unsigned short*)(ws + 32768);                // 37,748,736 B
  unsigned short* xpd = (unsigned short*)(ws + 32768 + 37748736);     // 35,684,352 B

  k_detect   <<<1, 256, 0, stream>>>((const unsigned short*)x, flag);
  k_style    <<<NB, 256, 0, stream>>>(style, mod_w, mod_b, flag, s_buf);
  k_weights  <<<dim3(COUT, NB), 256, 0, stream>>>(weight, s_buf, flag, Aw);
  k_transpose<<<dim3(66, NB), 256, 0, stream>>>(x, flag, xpd);
  k_gemm     <<<2048, 256, 0, stream>>>(Aw, xpd, flag, d_out);
}

// Round 4
// 386.463 us; speedup vs baseline: 1.2532x; 1.1155x over previous
//
#include <hip/hip_runtime.h>
#include <stdint.h>

#define CIN 256
#define COUT 128
#define SDIM 512
#define NB 16

// x_pad geometry: [b][66 rows][66 cols][256 ci] bf16
#define XP_RSTRIDE 16896          // 66*256
#define XP_BSTRIDE 1115136        // 66*66*256
// A geometry: [b][512 m][2304 k] bf16
#define A_BSTRIDE (512*2304)

typedef __attribute__((ext_vector_type(8))) short short8;
typedef __attribute__((ext_vector_type(4))) float f32x4;

__device__ __forceinline__ float bf2f(unsigned short h) {
  union { unsigned int u; float f; } v; v.u = ((unsigned int)h) << 16; return v.f;
}
__device__ __forceinline__ unsigned short f2bf(float f) {
  union { float f; unsigned int u; } v; v.f = f;
  return (unsigned short)((v.u + 0x7fffu + ((v.u >> 16) & 1u)) >> 16);
}
__device__ __forceinline__ void gll16(const void* g, void* l) {
  __builtin_amdgcn_global_load_lds(
      (const __attribute__((address_space(1))) unsigned int*)g,
      (__attribute__((address_space(3))) unsigned int*)l, 16, 0, 0);
}

// ---------------- kernel 0: dtype detector ----------------
__global__ __launch_bounds__(256) void k_detect(
    const unsigned short* __restrict__ xr, int* __restrict__ flag) {
  __shared__ int red[4];
  int t = threadIdx.x, cnt = 0;
  for (int i = t; i < 8192; i += 256) {
    int e = (xr[2*i] >> 7) & 0xff;
    cnt += (e > 90 && e < 145) ? 1 : 0;
  }
  #pragma unroll
  for (int off = 32; off > 0; off >>= 1) cnt += __shfl_down(cnt, off);
  if ((t & 63) == 0) red[t >> 6] = cnt;
  __syncthreads();
  if (t == 0) *flag = (red[0] + red[1] + red[2] + red[3] < 5000) ? 1 : 0;  // 1 = f32
}

// ---------------- kernel 1: s = style @ mod_w^T + mod_b ----------------
__global__ __launch_bounds__(256) void k_style(
    const void* __restrict__ style_v, const void* __restrict__ mod_w_v,
    const void* __restrict__ mod_b_v, const int* __restrict__ flag,
    float* __restrict__ s_out) {                // [16][256] f32
  __shared__ float st[SDIM];
  int b = blockIdx.x, t = threadIdx.x;
  int isf = *flag;
  float acc;
  if (!isf) {
    const unsigned short* style = (const unsigned short*)style_v;
    const unsigned short* mod_w = (const unsigned short*)mod_w_v;
    const unsigned short* mod_b = (const unsigned short*)mod_b_v;
    st[t]       = bf2f(style[b*SDIM + t]);
    st[t + 256] = bf2f(style[b*SDIM + t + 256]);
    __syncthreads();
    const uint4* wr = (const uint4*)(mod_w + (size_t)t*SDIM);
    acc = bf2f(mod_b[t]);
    #pragma unroll 4
    for (int s8 = 0; s8 < SDIM/8; ++s8) {
      uint4 p = wr[s8];
      int sb = s8*8;
      acc += bf2f((unsigned short)(p.x & 0xffff))*st[sb]
           + bf2f((unsigned short)(p.x >> 16))   *st[sb+1]
           + bf2f((unsigned short)(p.y & 0xffff))*st[sb+2]
           + bf2f((unsigned short)(p.y >> 16))   *st[sb+3]
           + bf2f((unsigned short)(p.z & 0xffff))*st[sb+4]
           + bf2f((unsigned short)(p.z >> 16))   *st[sb+5]
           + bf2f((unsigned short)(p.w & 0xffff))*st[sb+6]
           + bf2f((unsigned short)(p.w >> 16))   *st[sb+7];
    }
  } else {
    const float* style = (const float*)style_v;
    const float* mod_w = (const float*)mod_w_v;
    const float* mod_b = (const float*)mod_b_v;
    st[t]       = style[b*SDIM + t];
    st[t + 256] = style[b*SDIM + t + 256];
    __syncthreads();
    const float4* wr = (const float4*)(mod_w + (size_t)t*SDIM);
    acc = mod_b[t];
    #pragma unroll 4
    for (int s4 = 0; s4 < SDIM/4; ++s4) {
      float4 p = wr[s4];
      int sb = s4*4;
      acc += p.x*st[sb] + p.y*st[sb+1] + p.z*st[sb+2] + p.w*st[sb+3];
    }
  }
  s_out[b*CIN + t] = acc;
}

// ---------------- kernel 2: modulate+demod+blur-fold -> A[b][m][k] ----------------
// m = py*256 + co*2 + px ; k = tap*256 + ci, tap = (dh+1)*3+(dw+1)
__global__ __launch_bounds__(256) void k_weights(
    const void* __restrict__ weight_v,          // [128][256][3][3]
    const float* __restrict__ s_in,             // [16][256]
    const int* __restrict__ flag,
    unsigned short* __restrict__ Aw) {
  int co = blockIdx.x, b = blockIdx.y, ci = threadIdx.x;
  int isf = *flag;
  float sm = 0.0208333333333333f * s_in[b*CIN + ci];   // 1/48 = 1/sqrt(2304)
  float w9[9]; float ss = 0.f;
  if (!isf) {
    const unsigned short* wp = (const unsigned short*)weight_v + ((size_t)co*CIN + ci)*9;
    #pragma unroll
    for (int k = 0; k < 9; ++k) { float v = bf2f(wp[k]) * sm; w9[k] = v; ss += v*v; }
  } else {
    const float* wp = (const float*)weight_v + ((size_t)co*CIN + ci)*9;
    #pragma unroll
    for (int k = 0; k < 9; ++k) { float v = wp[k] * sm; w9[k] = v; ss += v*v; }
  }
  #pragma unroll
  for (int off = 32; off > 0; off >>= 1) ss += __shfl_down(ss, off);
  __shared__ float red[4];
  if ((ci & 63) == 0) red[ci >> 6] = ss;
  __syncthreads();
  float demod = rsqrtf(red[0] + red[1] + red[2] + red[3] + 1e-8f);
  #pragma unroll
  for (int k = 0; k < 9; ++k) w9[k] *= demod;
  const float F[4] = {0.25f, 0.75f, 0.75f, 0.25f};   // [1,3,3,1]/4 (x4 up-gain folded)
  float C6[6][6];
  #pragma unroll
  for (int ty = 0; ty < 6; ++ty) {
    #pragma unroll
    for (int tx = 0; tx < 6; ++tx) {
      float acc = 0.f;
      #pragma unroll
      for (int ay = 0; ay < 3; ++ay) {
        int fy = ay - ty + 3;
        if (fy < 0 || fy > 3) continue;
        float ra = 0.f;
        #pragma unroll
        for (int ax = 0; ax < 3; ++ax) {
          int fx = ax - tx + 3;
          if (fx < 0 || fx > 3) continue;
          ra += w9[ay*3 + ax] * F[fx];
        }
        acc += ra * F[fy];
      }
      C6[ty][tx] = acc;
    }
  }
  unsigned short* Ab = Aw + (size_t)b*A_BSTRIDE;
  #pragma unroll
  for (int py = 0; py < 2; ++py) {
    #pragma unroll
    for (int px = 0; px < 2; ++px) {
      unsigned short* Am = Ab + (size_t)(py*256 + co*2 + px)*2304 + ci;
      #pragma unroll
      for (int dh = -1; dh <= 1; ++dh) {
        #pragma unroll
        for (int dw = -1; dw <= 1; ++dw) {
          int tap = (dh+1)*3 + (dw+1);
          Am[tap*256] = f2bf(C6[py - 2*dh + 2][px - 2*dw + 2]);
        }
      }
    }
  }
}

// ---------------- kernel 3: x -> x_pad[b][r+1][c+1][ci] bf16, zero halo ----------------
// v2: dword-packed ci-pairs through LDS; conflict-free (2-way) both directions.
__global__ __launch_bounds__(256) void k_transpose(
    const void* __restrict__ x_v,   // [16][256][64][64] bf16 or f32
    const int* __restrict__ flag,
    unsigned short* __restrict__ xp) {
  int r_out = blockIdx.x, b = blockIdx.y, t = threadIdx.x;
  unsigned short* rp = xp + (size_t)b*XP_BSTRIDE + (size_t)r_out*XP_RSTRIDE;
  int r_in = r_out - 1;
  if (r_in < 0 || r_in >= 64) {          // border rows: all zero
    uint4 z = make_uint4(0,0,0,0);
    #pragma unroll
    for (int i = 0; i < 9; ++i) {
      int idx = i*256 + t;
      if (idx < 2112) ((uint4*)rp)[idx] = z;   // 16896 u16 = 2112 uint4
    }
    return;
  }
  if (t < 64) {                           // border cols 0 and 65: zero
    uint4 z = make_uint4(0,0,0,0);
    int col = (t < 32) ? 0 : 65;
    ((uint4*)(rp + col*256))[t & 31] = z;
  }
  int isf = *flag;
  __shared__ unsigned int lds32[64*33];   // [c 64][ci-pair 32], stride 33 dwords
  int tci = t >> 3;                       // ci-pair index 0..31
  int tc8 = t & 7;                        // c-octet 0..7
  int cS  = t >> 2;                       // store-side c 0..63
  int jg  = t & 3;                        // store-side ci chunk (16 ci)
  for (int g4 = 0; g4 < 4; ++g4) {
    int ci0 = g4 * 64;
    int ci = ci0 + tci*2;
    size_t base = (((size_t)b*CIN + ci)*64 + r_in)*64 + tc8*8;
    unsigned int v[8];
    if (isf) {
      const float* s0 = (const float*)x_v + base;
      const float* s1 = s0 + 4096;
      float4 a0 = ((const float4*)s0)[0], a1 = ((const float4*)s0)[1];
      float4 b0 = ((const float4*)s1)[0], b1 = ((const float4*)s1)[1];
      v[0] = f2bf(a0.x) | ((unsigned int)f2bf(b0.x) << 16);
      v[1] = f2bf(a0.y) | ((unsigned int)f2bf(b0.y) << 16);
      v[2] = f2bf(a0.z) | ((unsigned int)f2bf(b0.z) << 16);
      v[3] = f2bf(a0.w) | ((unsigned int)f2bf(b0.w) << 16);
      v[4] = f2bf(a1.x) | ((unsigned int)f2bf(b1.x) << 16);
      v[5] = f2bf(a1.y) | ((unsigned int)f2bf(b1.y) << 16);
      v[6] = f2bf(a1.z) | ((unsigned int)f2bf(b1.z) << 16);
      v[7] = f2bf(a1.w) | ((unsigned int)f2bf(b1.w) << 16);
    } else {
      const unsigned short* s0 = (const unsigned short*)x_v + base;
      const unsigned short* s1 = s0 + 4096;
      union { uint4 q; unsigned short h[8]; } u0, u1;
      u0.q = *(const uint4*)s0; u1.q = *(const uint4*)s1;
      #pragma unroll
      for (int j = 0; j < 8; ++j)
        v[j] = (unsigned int)u0.h[j] | ((unsigned int)u1.h[j] << 16);
    }
    if (g4) __syncthreads();
    #pragma unroll
    for (int j = 0; j < 8; ++j)
      lds32[(tc8*8 + j)*33 + tci] = v[j];
    __syncthreads();
    union { unsigned int o[8]; uint4 q[2]; } ob;
    #pragma unroll
    for (int w = 0; w < 8; ++w)
      ob.o[w] = lds32[cS*33 + jg*8 + w];
    uint4* dst = (uint4*)(rp + (size_t)(cS+1)*256 + ci0 + jg*16);
    dst[0] = ob.q[0];
    dst[1] = ob.q[1];
  }
}

// ---------------- kernel 4: implicit-GEMM subpixel conv ----------------
// v5: 8-phase-style 256x256 tile, BK=64, 8 waves (2m x 4n), 128x64 per wave.
// Raw s_barrier (no vmcnt drain) + COUNTED s_waitcnt vmcnt(8/4/0):
// 8-12 gll16 in flight at all times; waits never drain to 0 in steady state.
// setprio(1) around each 16-MFMA cluster. Per K-tile kt (buf D=kt&1): 4 phases
// (kh0/mq0, kh0/mq1, kh1/mq0, kh1/mq1). Phases 0-1 stage kh1 of tile kt+1 into
// buf E (read tile kt-1, done at tile-entry barrier). Phases 2-3 stage kh0 of
// tile kt+2 into buf D kh0 region (last read in phases 0-1 of THIS tile; all
// waves past phase-1-end barrier => safe). Mid-tile wait (before kh1 reads)
// ensures G1(kt) landed; tile-end wait ensures G0(kt+1) landed.
// LDS layout per half-tile: two [128 rows][32 k] sub-tiles with the proven
// source-permuted XOR k-chunk scheme (conflict-free reads; gll16-linear dest).
__global__ __launch_bounds__(512, 2) void k_gemm(
    const unsigned short* __restrict__ Aw,
    const unsigned short* __restrict__ xp,
    const int* __restrict__ flag,
    void* __restrict__ out) {
  __shared__ __align__(16) unsigned short As[2][2][8192];   // [buf][mhalf][kh*4096+row*32+part*8]
  __shared__ __align__(16) unsigned short Bs[2][2][8192];   // [buf][nhalf][...]
  int g = blockIdx.x;                  // 512 blocks
  int b  = ((g & 7) << 1) | ((g >> 3) & 1);   // 2 batch samples per XCD
  int mt = (g >> 4) & 1;               // m-tile (= py)
  int nt = g >> 5;                     // 0..15
  int yy0 = nt << 2;
  int t = threadIdx.x;
  int wave = t >> 6, lane = t & 63;
  int wm = wave >> 2, wn = wave & 3;   // 2m x 4n wave grid
  int wh = wn >> 1, wr = wn & 1;       // B half / row-base within half
  int l15 = lane & 15, q = lane >> 4;
  int qs = q ^ ((l15 >> 2) & 3);       // frag-read k-chunk swizzle
  int lOff = l15*32 + qs*8;
  int row = t >> 2, part = t & 3;      // staging: row 0..127, 16B part 0..3
  int partS = part ^ ((row >> 2) & 3); // source-permuted chunk (write side)
  int dst8 = t * 8;                    // thread-linear 16B LDS slots
  int isf = *flag;

  const unsigned short* pA0 = Aw + (size_t)b*A_BSTRIDE + (size_t)(mt*256 + row)*2304 + partS*8;
  const unsigned short* pA1 = pA0 + (size_t)128*2304;
  const unsigned short* pB0 = xp + (size_t)b*XP_BSTRIDE
      + (size_t)(yy0 + (row >> 6) + 1)*XP_RSTRIDE + (size_t)((row & 63) + 1)*256 + partS*8;
  const unsigned short* pB1 = pB0 + (size_t)2*XP_RSTRIDE;

  f32x4 acc[8][4];
  #pragma unroll
  for (int i = 0; i < 8; ++i)
    #pragma unroll
    for (int j = 0; j < 4; ++j)
      acc[i][j] = (f32x4){0.f, 0.f, 0.f, 0.f};

  #define BARR() do { asm volatile("" ::: "memory"); __builtin_amdgcn_s_barrier(); \
                      __builtin_amdgcn_sched_barrier(0); } while (0)
  #define LGKM0() do { asm volatile("s_waitcnt lgkmcnt(0)" ::: "memory"); \
                       __builtin_amdgcn_sched_barrier(0); } while (0)
  #define WVM8() do { asm volatile("s_waitcnt vmcnt(8)" ::: "memory"); \
                      __builtin_amdgcn_sched_barrier(0); } while (0)
  #define WVM4() do { asm volatile("s_waitcnt vmcnt(4)" ::: "memory"); \
                      __builtin_amdgcn_sched_barrier(0); } while (0)
  #define WVM0() do { asm volatile("s_waitcnt vmcnt(0)" ::: "memory"); \
                      __builtin_amdgcn_sched_barrier(0); } while (0)

  // A k-offset is fully linear: k = KT*64 + KH*32 (+chunk). B needs tap decode.
  #define STG_A(D, H, KH, KT) gll16(pA##H + (KT)*64 + (KH)*32, &As[D][H][(KH)*4096 + dst8]);
  #define STG_B(D, H, KH, KT, DH, DW) \
    gll16(pB##H + (DH)*XP_RSTRIDE + (DW)*256 + ((KT)&3)*64 + (KH)*32, \
          &Bs[D][H][(KH)*4096 + dst8]);

  #define PH_READ_B(D, KH) { \
    _Pragma("unroll") \
    for (int j_ = 0; j_ < 4; ++j_) \
      bv[j_] = *(const short8*)&Bs[D][wh][(KH)*4096 + wr*2048 + j_*512 + lOff]; }
  #define PH_READ_A(D, KH, MQ) { \
    _Pragma("unroll") \
    for (int i_ = 0; i_ < 4; ++i_) \
      af[i_] = *(const short8*)&As[D][wm][(KH)*4096 + (MQ)*2048 + i_*512 + lOff]; }
  #define PH_MFMA(MQ) { \
    __builtin_amdgcn_s_setprio(1); \
    _Pragma("unroll") \
    for (int j_ = 0; j_ < 4; ++j_) \
      _Pragma("unroll") \
      for (int i_ = 0; i_ < 4; ++i_) \
        acc[(MQ)*4 + i_][j_] = __builtin_amdgcn_mfma_f32_16x16x32_bf16( \
            af[i_], bv[j_], acc[(MQ)*4 + i_][j_], 0, 0, 0); \
    __builtin_amdgcn_s_setprio(0); \
    __builtin_amdgcn_sched_barrier(0); }

  // One K-tile: D/E compile-time buffer indices; DO1 stages G1(KT+1), DO0 stages G0(KT+2).
  #define TILE(KT, D, E, DO1, DO0, WMID, WEND, DOEND) { \
    const int kt1_ = (KT) + 1, kt2_ = (KT) + 2; \
    int tap1_ = kt1_ >> 2; \
    int dh1_ = (tap1_ >= 6) ? 1 : ((tap1_ >= 3) ? 0 : -1); \
    int dw1_ = tap1_ - (dh1_ + 1)*3 - 1; \
    int tap2_ = kt2_ >> 2; \
    int dh2_ = (tap2_ >= 6) ? 1 : ((tap2_ >= 3) ? 0 : -1); \
    int dw2_ = tap2_ - (dh2_ + 1)*3 - 1; \
    short8 af[4], bv[4]; \
    /* phase 0: kh0/mq0 (loads B kh0) */ \
    PH_READ_B(D, 0); PH_READ_A(D, 0, 0); \
    if (DO1) { STG_A(E, 0, 1, kt1_); STG_A(E, 1, 1, kt1_); } \
    BARR(); LGKM0(); PH_MFMA(0); BARR(); \
    /* phase 1: kh0/mq1 (reuses bv) */ \
    PH_READ_A(D, 0, 1); \
    if (DO1) { STG_B(E, 0, 1, kt1_, dh1_, dw1_); STG_B(E, 1, 1, kt1_, dh1_, dw1_); } \
    BARR(); LGKM0(); PH_MFMA(1); \
    WMID; BARR(); \
    /* phase 2: kh1/mq0 */ \
    PH_READ_B(D, 1); PH_READ_A(D, 1, 0); \
    if (DO0) { STG_A(D, 0, 0, kt2_); STG_A(D, 1, 0, kt2_); } \
    BARR(); LGKM0(); PH_MFMA(0); BARR(); \
    /* phase 3: kh1/mq1 */ \
    PH_READ_A(D, 1, 1); \
    if (DO0) { STG_B(D, 0, 0, kt2_, dh2_, dw2_); STG_B(D, 1, 0, kt2_, dh2_, dw2_); } \
    BARR(); LGKM0(); PH_MFMA(1); \
    if (DOEND) { WEND; BARR(); } \
  }

  // PROLOGUE: G0(0) [oldest 4], G1(0), G0(1) -> 12 in flight; wait oldest 4.
  // kt=0,1 -> tap 0 (dh=-1, dw=-1).
  STG_A(0, 0, 0, 0); STG_A(0, 1, 0, 0);
  STG_B(0, 0, 0, 0, -1, -1); STG_B(0, 1, 0, 0, -1, -1);
  STG_A(0, 0, 1, 0); STG_A(0, 1, 1, 0);
  STG_B(0, 0, 1, 0, -1, -1); STG_B(0, 1, 1, 0, -1, -1);
  STG_A(1, 0, 0, 1); STG_A(1, 1, 0, 1);
  STG_B(1, 0, 0, 1, -1, -1); STG_B(1, 1, 0, 1, -1, -1);
  WVM8(); BARR();

  // MAIN: 36 K-tiles (9 taps x 4). Tiles 0..33 full pipeline; 34/35 peeled tail.
  #pragma unroll 1
  for (int kt = 0; kt < 34; kt += 2) {
    TILE(kt,     0, 1, 1, 1, WVM8(), WVM8(), 1);
    TILE(kt + 1, 1, 0, 1, 1, WVM8(), WVM8(), 1);
  }
  TILE(34, 0, 1, 1, 0, WVM8(), WVM4(), 1);
  TILE(35, 1, 0, 0, 0, WVM0(), WVM0(), 0);

  #undef TILE
  #undef PH_MFMA
  #undef PH_READ_A
  #undef PH_READ_B
  #undef STG_B
  #undef STG_A

  // EPILOGUE: m = mt*256 + wm*128 + (ig>>2)*64 + (ig&3)*16 + q*4 + rr*2 + px
  //   => py = mt, co = wm*64 + (ig>>2)*32 + (ig&3)*8 + q*2 + rr, px = reg parity
  // n = nt*256 + wn*64 + j*16 + l15 => yy = nt*4 + wn, xc = j*16 + l15
  // y = 2*yy + py, x = 2*xc + px (px-pair packed per store)
  int y = 8*nt + 2*wn + mt;
  if (!isf) {
    unsigned int* outp = (unsigned int*)out;
    #pragma unroll
    for (int ig = 0; ig < 8; ++ig) {
      #pragma unroll
      for (int rr = 0; rr < 2; ++rr) {
        int co = wm*64 + (ig >> 2)*32 + (ig & 3)*8 + q*2 + rr;
        size_t obase = (((size_t)b*COUT + co)*128 + y)*64;
        #pragma unroll
        for (int j = 0; j < 4; ++j) {
          unsigned int pk = (unsigned int)f2bf(acc[ig][j][rr*2])
                          | ((unsigned int)f2bf(acc[ig][j][rr*2 + 1]) << 16);
          outp[obase + j*16 + l15] = pk;
        }
      }
    }
  } else {
    float2* outp = (float2*)out;
    #pragma unroll
    for (int ig = 0; ig < 8; ++ig) {
      #pragma unroll
      for (int rr = 0; rr < 2; ++rr) {
        int co = wm*64 + (ig >> 2)*32 + (ig & 3)*8 + q*2 + rr;
        size_t obase = (((size_t)b*COUT + co)*128 + y)*64;
        #pragma unroll
        for (int j = 0; j < 4; ++j)
          outp[obase + j*16 + l15] = make_float2(acc[ig][j][rr*2], acc[ig][j][rr*2 + 1]);
      }
    }
  }
  #undef BARR
  #undef LGKM0
  #undef WVM8
  #undef WVM4
  #undef WVM0
}

extern "C" void kernel_launch(void* const* d_in, const int* in_sizes, int n_in,
                              void* d_out, int out_size, void* d_ws, size_t ws_size,
                              hipStream_t stream) {
  const void* x      = d_in[0];
  const void* style  = d_in[1];
  const void* weight = d_in[2];
  const void* mod_w  = d_in[3];
  const void* mod_b  = d_in[4];
  char* ws = (char*)d_ws;
  int* flag           = (int*)ws;                                     // 4 B
  float* s_buf        = (float*)(ws + 1024);                          // 16 KB
  unsigned short* Aw  = (unsigned short*)(ws + 32768);                // 37,748,736 B
  unsigned short* xpd = (unsigned short*)(ws + 32768 + 37748736);     // 35,684,352 B

  k_detect   <<<1, 256, 0, stream>>>((const unsigned short*)x, flag);
  k_style    <<<NB, 256, 0, stream>>>(style, mod_w, mod_b, flag, s_buf);
  k_weights  <<<dim3(COUT, NB), 256, 0, stream>>>(weight, s_buf, flag, Aw);
  k_transpose<<<dim3(66, NB), 256, 0, stream>>>(x, flag, xpd);
  k_gemm     <<<512, 512, 0, stream>>>(Aw, xpd, flag, d_out);
}

// Round 5
// 367.412 us; speedup vs baseline: 1.3182x; 1.0519x over previous
//
#include <hip/hip_runtime.h>
#include <stdint.h>

#define CIN 256
#define COUT 128
#define SDIM 512
#define NB 16

// x_pad geometry: [b][66 rows][66 cols][256 ci] bf16
#define XP_RSTRIDE 16896          // 66*256
#define XP_BSTRIDE 1115136        // 66*66*256
// A geometry: [b][512 m][2304 k] bf16
#define A_BSTRIDE (512*2304)

typedef __attribute__((ext_vector_type(8))) short short8;
typedef __attribute__((ext_vector_type(4))) float f32x4;

__device__ __forceinline__ float bf2f(unsigned short h) {
  union { unsigned int u; float f; } v; v.u = ((unsigned int)h) << 16; return v.f;
}
__device__ __forceinline__ unsigned short f2bf(float f) {
  union { float f; unsigned int u; } v; v.f = f;
  return (unsigned short)((v.u + 0x7fffu + ((v.u >> 16) & 1u)) >> 16);
}
__device__ __forceinline__ void gll16(const void* g, void* l) {
  __builtin_amdgcn_global_load_lds(
      (const __attribute__((address_space(1))) unsigned int*)g,
      (__attribute__((address_space(3))) unsigned int*)l, 16, 0, 0);
}

// ---------------- kernel 0: dtype detector ----------------
__global__ __launch_bounds__(256) void k_detect(
    const unsigned short* __restrict__ xr, int* __restrict__ flag) {
  __shared__ int red[4];
  int t = threadIdx.x, cnt = 0;
  for (int i = t; i < 8192; i += 256) {
    int e = (xr[2*i] >> 7) & 0xff;
    cnt += (e > 90 && e < 145) ? 1 : 0;
  }
  #pragma unroll
  for (int off = 32; off > 0; off >>= 1) cnt += __shfl_down(cnt, off);
  if ((t & 63) == 0) red[t >> 6] = cnt;
  __syncthreads();
  if (t == 0) *flag = (red[0] + red[1] + red[2] + red[3] < 5000) ? 1 : 0;  // 1 = f32
}

// ---------------- kernel 1: s = style @ mod_w^T + mod_b ----------------
__global__ __launch_bounds__(256) void k_style(
    const void* __restrict__ style_v, const void* __restrict__ mod_w_v,
    const void* __restrict__ mod_b_v, const int* __restrict__ flag,
    float* __restrict__ s_out) {                // [16][256] f32
  __shared__ float st[SDIM];
  int b = blockIdx.x, t = threadIdx.x;
  int isf = *flag;
  float acc;
  if (!isf) {
    const unsigned short* style = (const unsigned short*)style_v;
    const unsigned short* mod_w = (const unsigned short*)mod_w_v;
    const unsigned short* mod_b = (const unsigned short*)mod_b_v;
    st[t]       = bf2f(style[b*SDIM + t]);
    st[t + 256] = bf2f(style[b*SDIM + t + 256]);
    __syncthreads();
    const uint4* wr = (const uint4*)(mod_w + (size_t)t*SDIM);
    acc = bf2f(mod_b[t]);
    #pragma unroll 4
    for (int s8 = 0; s8 < SDIM/8; ++s8) {
      uint4 p = wr[s8];
      int sb = s8*8;
      acc += bf2f((unsigned short)(p.x & 0xffff))*st[sb]
           + bf2f((unsigned short)(p.x >> 16))   *st[sb+1]
           + bf2f((unsigned short)(p.y & 0xffff))*st[sb+2]
           + bf2f((unsigned short)(p.y >> 16))   *st[sb+3]
           + bf2f((unsigned short)(p.z & 0xffff))*st[sb+4]
           + bf2f((unsigned short)(p.z >> 16))   *st[sb+5]
           + bf2f((unsigned short)(p.w & 0xffff))*st[sb+6]
           + bf2f((unsigned short)(p.w >> 16))   *st[sb+7];
    }
  } else {
    const float* style = (const float*)style_v;
    const float* mod_w = (const float*)mod_w_v;
    const float* mod_b = (const float*)mod_b_v;
    st[t]       = style[b*SDIM + t];
    st[t + 256] = style[b*SDIM + t + 256];
    __syncthreads();
    const float4* wr = (const float4*)(mod_w + (size_t)t*SDIM);
    acc = mod_b[t];
    #pragma unroll 4
    for (int s4 = 0; s4 < SDIM/4; ++s4) {
      float4 p = wr[s4];
      int sb = s4*4;
      acc += p.x*st[sb] + p.y*st[sb+1] + p.z*st[sb+2] + p.w*st[sb+3];
    }
  }
  s_out[b*CIN + t] = acc;
}

// ---------------- kernel 2: modulate+demod+blur-fold -> A[b][m][k] ----------------
// m = py*256 + co*2 + px ; k = tap*256 + ci, tap = (dh+1)*3+(dw+1)
__global__ __launch_bounds__(256) void k_weights(
    const void* __restrict__ weight_v,          // [128][256][3][3]
    const float* __restrict__ s_in,             // [16][256]
    const int* __restrict__ flag,
    unsigned short* __restrict__ Aw) {
  int co = blockIdx.x, b = blockIdx.y, ci = threadIdx.x;
  int isf = *flag;
  float sm = 0.0208333333333333f * s_in[b*CIN + ci];   // 1/48 = 1/sqrt(2304)
  float w9[9]; float ss = 0.f;
  if (!isf) {
    const unsigned short* wp = (const unsigned short*)weight_v + ((size_t)co*CIN + ci)*9;
    #pragma unroll
    for (int k = 0; k < 9; ++k) { float v = bf2f(wp[k]) * sm; w9[k] = v; ss += v*v; }
  } else {
    const float* wp = (const float*)weight_v + ((size_t)co*CIN + ci)*9;
    #pragma unroll
    for (int k = 0; k < 9; ++k) { float v = wp[k] * sm; w9[k] = v; ss += v*v; }
  }
  #pragma unroll
  for (int off = 32; off > 0; off >>= 1) ss += __shfl_down(ss, off);
  __shared__ float red[4];
  if ((ci & 63) == 0) red[ci >> 6] = ss;
  __syncthreads();
  float demod = rsqrtf(red[0] + red[1] + red[2] + red[3] + 1e-8f);
  #pragma unroll
  for (int k = 0; k < 9; ++k) w9[k] *= demod;
  const float F[4] = {0.25f, 0.75f, 0.75f, 0.25f};   // [1,3,3,1]/4 (x4 up-gain folded)
  float C6[6][6];
  #pragma unroll
  for (int ty = 0; ty < 6; ++ty) {
    #pragma unroll
    for (int tx = 0; tx < 6; ++tx) {
      float acc = 0.f;
      #pragma unroll
      for (int ay = 0; ay < 3; ++ay) {
        int fy = ay - ty + 3;
        if (fy < 0 || fy > 3) continue;
        float ra = 0.f;
        #pragma unroll
        for (int ax = 0; ax < 3; ++ax) {
          int fx = ax - tx + 3;
          if (fx < 0 || fx > 3) continue;
          ra += w9[ay*3 + ax] * F[fx];
        }
        acc += ra * F[fy];
      }
      C6[ty][tx] = acc;
    }
  }
  unsigned short* Ab = Aw + (size_t)b*A_BSTRIDE;
  #pragma unroll
  for (int py = 0; py < 2; ++py) {
    #pragma unroll
    for (int px = 0; px < 2; ++px) {
      unsigned short* Am = Ab + (size_t)(py*256 + co*2 + px)*2304 + ci;
      #pragma unroll
      for (int dh = -1; dh <= 1; ++dh) {
        #pragma unroll
        for (int dw = -1; dw <= 1; ++dw) {
          int tap = (dh+1)*3 + (dw+1);
          Am[tap*256] = f2bf(C6[py - 2*dh + 2][px - 2*dw + 2]);
        }
      }
    }
  }
}

// ---------------- kernel 3: x -> x_pad[b][r+1][c+1][ci] bf16, zero halo ----------------
// v2: dword-packed ci-pairs through LDS; conflict-free (2-way) both directions.
__global__ __launch_bounds__(256) void k_transpose(
    const void* __restrict__ x_v,   // [16][256][64][64] bf16 or f32
    const int* __restrict__ flag,
    unsigned short* __restrict__ xp) {
  int r_out = blockIdx.x, b = blockIdx.y, t = threadIdx.x;
  unsigned short* rp = xp + (size_t)b*XP_BSTRIDE + (size_t)r_out*XP_RSTRIDE;
  int r_in = r_out - 1;
  if (r_in < 0 || r_in >= 64) {          // border rows: all zero
    uint4 z = make_uint4(0,0,0,0);
    #pragma unroll
    for (int i = 0; i < 9; ++i) {
      int idx = i*256 + t;
      if (idx < 2112) ((uint4*)rp)[idx] = z;   // 16896 u16 = 2112 uint4
    }
    return;
  }
  if (t < 64) {                           // border cols 0 and 65: zero
    uint4 z = make_uint4(0,0,0,0);
    int col = (t < 32) ? 0 : 65;
    ((uint4*)(rp + col*256))[t & 31] = z;
  }
  int isf = *flag;
  __shared__ unsigned int lds32[64*33];   // [c 64][ci-pair 32], stride 33 dwords
  int tci = t >> 3;                       // ci-pair index 0..31
  int tc8 = t & 7;                        // c-octet 0..7
  int cS  = t >> 2;                       // store-side c 0..63
  int jg  = t & 3;                        // store-side ci chunk (16 ci)
  for (int g4 = 0; g4 < 4; ++g4) {
    int ci0 = g4 * 64;
    int ci = ci0 + tci*2;
    size_t base = (((size_t)b*CIN + ci)*64 + r_in)*64 + tc8*8;
    unsigned int v[8];
    if (isf) {
      const float* s0 = (const float*)x_v + base;
      const float* s1 = s0 + 4096;
      float4 a0 = ((const float4*)s0)[0], a1 = ((const float4*)s0)[1];
      float4 b0 = ((const float4*)s1)[0], b1 = ((const float4*)s1)[1];
      v[0] = f2bf(a0.x) | ((unsigned int)f2bf(b0.x) << 16);
      v[1] = f2bf(a0.y) | ((unsigned int)f2bf(b0.y) << 16);
      v[2] = f2bf(a0.z) | ((unsigned int)f2bf(b0.z) << 16);
      v[3] = f2bf(a0.w) | ((unsigned int)f2bf(b0.w) << 16);
      v[4] = f2bf(a1.x) | ((unsigned int)f2bf(b1.x) << 16);
      v[5] = f2bf(a1.y) | ((unsigned int)f2bf(b1.y) << 16);
      v[6] = f2bf(a1.z) | ((unsigned int)f2bf(b1.z) << 16);
      v[7] = f2bf(a1.w) | ((unsigned int)f2bf(b1.w) << 16);
    } else {
      const unsigned short* s0 = (const unsigned short*)x_v + base;
      const unsigned short* s1 = s0 + 4096;
      union { uint4 q; unsigned short h[8]; } u0, u1;
      u0.q = *(const uint4*)s0; u1.q = *(const uint4*)s1;
      #pragma unroll
      for (int j = 0; j < 8; ++j)
        v[j] = (unsigned int)u0.h[j] | ((unsigned int)u1.h[j] << 16);
    }
    if (g4) __syncthreads();
    #pragma unroll
    for (int j = 0; j < 8; ++j)
      lds32[(tc8*8 + j)*33 + tci] = v[j];
    __syncthreads();
    union { unsigned int o[8]; uint4 q[2]; } ob;
    #pragma unroll
    for (int w = 0; w < 8; ++w)
      ob.o[w] = lds32[cS*33 + jg*8 + w];
    uint4* dst = (uint4*)(rp + (size_t)(cS+1)*256 + ci0 + jg*16);
    dst[0] = ob.q[0];
    dst[1] = ob.q[1];
  }
}

// ---------------- kernel 4: implicit-GEMM subpixel conv ----------------
// v6: same 256x256/BK64/8-wave geometry as v5, but REGISTER FRAG DOUBLE-BUFFER
// one phase ahead: each phase issues ds_reads for phase P+1 (alt frag set),
// stages 2 gll16, then MFMAs on frags read last phase (compiler emits the
// counted lgkm wait for the operands). LDS-read drain overlaps MFMA.
// Gates shift one phase earlier: uniform vmcnt(6)+barrier at P1/P3 entry;
// barriers per tile: 4 (P1-entry, P1-end, P3-entry, P3-end).
// Region audit: every region's last reader completes (its lgkm wait) before a
// barrier that precedes the overwriting stage-issue. Stage cadence (=v5):
// P0/P1 stage kh1(kt+1)->E, P2/P3 stage kh0(kt+2)->D.
__global__ __launch_bounds__(512, 2) void k_gemm(
    const unsigned short* __restrict__ Aw,
    const unsigned short* __restrict__ xp,
    const int* __restrict__ flag,
    void* __restrict__ out) {
  __shared__ __align__(16) unsigned short As[2][2][8192];   // [buf][mhalf][kh*4096+slot]
  __shared__ __align__(16) unsigned short Bs[2][2][8192];   // [buf][nhalf][...]
  int g = blockIdx.x;                  // 512 blocks
  int b  = ((g & 7) << 1) | ((g >> 3) & 1);   // 2 batch samples per XCD
  int mt = (g >> 4) & 1;               // m-tile (= py)
  int nt = g >> 5;                     // 0..15
  int yy0 = nt << 2;
  int t = threadIdx.x;
  int wave = t >> 6, lane = t & 63;
  int wm = wave >> 2, wn = wave & 3;   // 2m x 4n wave grid
  int wh = wn >> 1, wr = wn & 1;       // B half / row-base within half
  int l15 = lane & 15, q = lane >> 4;
  int qs = q ^ ((l15 >> 2) & 3);       // frag-read k-chunk swizzle
  int lOff = l15*32 + qs*8;
  int row = t >> 2, part = t & 3;      // staging: row 0..127, 16B part 0..3
  int partS = part ^ ((row >> 2) & 3); // source-permuted chunk (write side)
  int dst8 = t * 8;                    // thread-linear 16B LDS slots
  int isf = *flag;

  const unsigned short* pA0 = Aw + (size_t)b*A_BSTRIDE + (size_t)(mt*256 + row)*2304 + partS*8;
  const unsigned short* pA1 = pA0 + (size_t)128*2304;
  const unsigned short* pB0 = xp + (size_t)b*XP_BSTRIDE
      + (size_t)(yy0 + (row >> 6) + 1)*XP_RSTRIDE + (size_t)((row & 63) + 1)*256 + partS*8;
  const unsigned short* pB1 = pB0 + (size_t)2*XP_RSTRIDE;

  f32x4 acc[8][4];
  #pragma unroll
  for (int i = 0; i < 8; ++i)
    #pragma unroll
    for (int j = 0; j < 4; ++j)
      acc[i][j] = (f32x4){0.f, 0.f, 0.f, 0.f};

  // register frag sets (all statically named; no dynamic indexing)
  short8 afA0, afA1, afA2, afA3;   // loaded in P3/P1 (mq0 sets)
  short8 afB0, afB1, afB2, afB3;   // loaded in P0/P2 (mq1 sets)
  short8 bvA0, bvA1, bvA2, bvA3;   // kh0 B-frags (loaded P3 of prev tile)
  short8 bvB0, bvB1, bvB2, bvB3;   // kh1 B-frags (loaded P1)

  #define BARR() do { asm volatile("" ::: "memory"); __builtin_amdgcn_s_barrier(); \
                      __builtin_amdgcn_sched_barrier(0); } while (0)
  #define SCHED0() __builtin_amdgcn_sched_barrier(0)
  #define WVM8() do { asm volatile("s_waitcnt vmcnt(8)" ::: "memory"); } while (0)
  #define WVM6() do { asm volatile("s_waitcnt vmcnt(6)" ::: "memory"); } while (0)
  #define WVM4() do { asm volatile("s_waitcnt vmcnt(4)" ::: "memory"); } while (0)
  #define WVM0() do { asm volatile("s_waitcnt vmcnt(0)" ::: "memory"); } while (0)

  #define STG_A(D, H, KH, KT) gll16(pA##H + (KT)*64 + (KH)*32, &As[D][H][(KH)*4096 + dst8]);
  #define STG_B(D, H, KH, KT, DH, DW) \
    gll16(pB##H + (DH)*XP_RSTRIDE + (DW)*256 + ((KT)&3)*64 + (KH)*32, \
          &Bs[D][H][(KH)*4096 + dst8]);

  #define RD_B(D, KH, V0, V1, V2, V3) { \
    V0 = *(const short8*)&Bs[D][wh][(KH)*4096 + wr*2048 + 0*512 + lOff]; \
    V1 = *(const short8*)&Bs[D][wh][(KH)*4096 + wr*2048 + 1*512 + lOff]; \
    V2 = *(const short8*)&Bs[D][wh][(KH)*4096 + wr*2048 + 2*512 + lOff]; \
    V3 = *(const short8*)&Bs[D][wh][(KH)*4096 + wr*2048 + 3*512 + lOff]; }
  #define RD_A(D, KH, MQ, V0, V1, V2, V3) { \
    V0 = *(const short8*)&As[D][wm][(KH)*4096 + (MQ)*2048 + 0*512 + lOff]; \
    V1 = *(const short8*)&As[D][wm][(KH)*4096 + (MQ)*2048 + 1*512 + lOff]; \
    V2 = *(const short8*)&As[D][wm][(KH)*4096 + (MQ)*2048 + 2*512 + lOff]; \
    V3 = *(const short8*)&As[D][wm][(KH)*4096 + (MQ)*2048 + 3*512 + lOff]; }

  #define MROW(AF, B0, B1, B2, B3, R) \
    acc[R][0] = __builtin_amdgcn_mfma_f32_16x16x32_bf16(AF, B0, acc[R][0], 0, 0, 0); \
    acc[R][1] = __builtin_amdgcn_mfma_f32_16x16x32_bf16(AF, B1, acc[R][1], 0, 0, 0); \
    acc[R][2] = __builtin_amdgcn_mfma_f32_16x16x32_bf16(AF, B2, acc[R][2], 0, 0, 0); \
    acc[R][3] = __builtin_amdgcn_mfma_f32_16x16x32_bf16(AF, B3, acc[R][3], 0, 0, 0);
  #define MFMA16(A0, A1, A2, A3, B0, B1, B2, B3, MQ) { \
    __builtin_amdgcn_s_setprio(1); \
    MROW(A0, B0, B1, B2, B3, (MQ)*4 + 0) \
    MROW(A1, B0, B1, B2, B3, (MQ)*4 + 1) \
    MROW(A2, B0, B1, B2, B3, (MQ)*4 + 2) \
    MROW(A3, B0, B1, B2, B3, (MQ)*4 + 3) \
    __builtin_amdgcn_s_setprio(0); \
    SCHED0(); }

  // TILE: D = buf of this tile (kt&1), E = other buf.
  // W1N/W2N: vmcnt gate values; DO1: stage kh1(kt+1); DO0: stage kh0(kt+2);
  // LAST: final tile (skip P3 next-tile reads).
  #define TILE(KT, D, E, DO1, DO0, W1, W2, LAST) { \
    const int kt1_ = (KT) + 1, kt2_ = (KT) + 2; \
    int tap1_ = kt1_ >> 2; \
    int dh1_ = (tap1_ >= 6) ? 1 : ((tap1_ >= 3) ? 0 : -1); \
    int dw1_ = tap1_ - (dh1_ + 1)*3 - 1; \
    int tap2_ = kt2_ >> 2; \
    int dh2_ = (tap2_ >= 6) ? 1 : ((tap2_ >= 3) ? 0 : -1); \
    int dw2_ = tap2_ - (dh2_ + 1)*3 - 1; \
    /* P0: consume (afA,bvA)=kh0/mq0; read A kh0/mq1 */ \
    RD_A(D, 0, 1, afB0, afB1, afB2, afB3); \
    if (DO1) { STG_A(E, 0, 1, kt1_); STG_A(E, 1, 1, kt1_); } \
    SCHED0(); \
    MFMA16(afA0, afA1, afA2, afA3, bvA0, bvA1, bvA2, bvA3, 0); \
    /* P1: gate kh1(kt); consume (afB,bvA)=kh0/mq1; read B kh1 + A kh1/mq0 */ \
    W1; BARR(); \
    RD_B(D, 1, bvB0, bvB1, bvB2, bvB3); \
    RD_A(D, 1, 0, afA0, afA1, afA2, afA3); \
    if (DO1) { STG_B(E, 0, 1, kt1_, dh1_, dw1_); STG_B(E, 1, 1, kt1_, dh1_, dw1_); } \
    SCHED0(); \
    MFMA16(afB0, afB1, afB2, afB3, bvA0, bvA1, bvA2, bvA3, 1); \
    BARR(); \
    /* P2: consume (afA,bvB)=kh1/mq0; read A kh1/mq1 */ \
    RD_A(D, 1, 1, afB0, afB1, afB2, afB3); \
    if (DO0) { STG_A(D, 0, 0, kt2_); STG_A(D, 1, 0, kt2_); } \
    SCHED0(); \
    MFMA16(afA0, afA1, afA2, afA3, bvB0, bvB1, bvB2, bvB3, 0); \
    /* P3: gate kh0(kt+1); consume (afB,bvB)=kh1/mq1; read next-tile kh0 frags */ \
    W2; BARR(); \
    if (!(LAST)) { \
      RD_B(E, 0, bvA0, bvA1, bvA2, bvA3); \
      RD_A(E, 0, 0, afA0, afA1, afA2, afA3); \
    } \
    if (DO0) { STG_B(D, 0, 0, kt2_, dh2_, dw2_); STG_B(D, 1, 0, kt2_, dh2_, dw2_); } \
    SCHED0(); \
    MFMA16(afB0, afB1, afB2, afB3, bvB0, bvB1, bvB2, bvB3, 1); \
    BARR(); \
  }

  // PROLOGUE: stage kh0(0), kh1(0), kh0(1) (12 loads); gate oldest 4; preload P0(0) frags.
  STG_A(0, 0, 0, 0); STG_A(0, 1, 0, 0);
  STG_B(0, 0, 0, 0, -1, -1); STG_B(0, 1, 0, 0, -1, -1);
  STG_A(0, 0, 1, 0); STG_A(0, 1, 1, 0);
  STG_B(0, 0, 1, 0, -1, -1); STG_B(0, 1, 1, 0, -1, -1);
  STG_A(1, 0, 0, 1); STG_A(1, 1, 0, 1);
  STG_B(1, 0, 0, 1, -1, -1); STG_B(1, 1, 0, 1, -1, -1);
  WVM8(); BARR();
  RD_B(0, 0, bvA0, bvA1, bvA2, bvA3);
  RD_A(0, 0, 0, afA0, afA1, afA2, afA3);
  SCHED0();

  // MAIN: 36 K-tiles (9 taps x 4). Steady gates vmcnt(6); tail recounted.
  #pragma unroll 1
  for (int kt = 0; kt < 34; kt += 2) {
    TILE(kt,     0, 1, 1, 1, WVM6(), WVM6(), 0);
    TILE(kt + 1, 1, 0, 1, 1, WVM6(), WVM6(), 0);
  }
  TILE(34, 0, 1, 1, 0, WVM6(), WVM4(), 0);
  TILE(35, 1, 0, 0, 0, WVM0(), WVM0(), 1);

  #undef TILE
  #undef MFMA16
  #undef MROW
  #undef RD_A
  #undef RD_B
  #undef STG_B
  #undef STG_A

  // EPILOGUE: m = mt*256 + wm*128 + (ig>>2)*64 + (ig&3)*16 + q*4 + rr*2 + px
  //   => py = mt, co = wm*64 + (ig>>2)*32 + (ig&3)*8 + q*2 + rr, px = reg parity
  // n = nt*256 + wn*64 + j*16 + l15 => yy = nt*4 + wn, xc = j*16 + l15
  int y = 8*nt + 2*wn + mt;
  if (!isf) {
    unsigned int* outp = (unsigned int*)out;
    #pragma unroll
    for (int ig = 0; ig < 8; ++ig) {
      #pragma unroll
      for (int rr = 0; rr < 2; ++rr) {
        int co = wm*64 + (ig >> 2)*32 + (ig & 3)*8 + q*2 + rr;
        size_t obase = (((size_t)b*COUT + co)*128 + y)*64;
        #pragma unroll
        for (int j = 0; j < 4; ++j) {
          unsigned int pk = (unsigned int)f2bf(acc[ig][j][rr*2])
                          | ((unsigned int)f2bf(acc[ig][j][rr*2 + 1]) << 16);
          outp[obase + j*16 + l15] = pk;
        }
      }
    }
  } else {
    float2* outp = (float2*)out;
    #pragma unroll
    for (int ig = 0; ig < 8; ++ig) {
      #pragma unroll
      for (int rr = 0; rr < 2; ++rr) {
        int co = wm*64 + (ig >> 2)*32 + (ig & 3)*8 + q*2 + rr;
        size_t obase = (((size_t)b*COUT + co)*128 + y)*64;
        #pragma unroll
        for (int j = 0; j < 4; ++j)
          outp[obase + j*16 + l15] = make_float2(acc[ig][j][rr*2], acc[ig][j][rr*2 + 1]);
      }
    }
  }
  #undef BARR
  #undef SCHED0
  #undef WVM8
  #undef WVM6
  #undef WVM4
  #undef WVM0
}

extern "C" void kernel_launch(void* const* d_in, const int* in_sizes, int n_in,
                              void* d_out, int out_size, void* d_ws, size_t ws_size,
                              hipStream_t stream) {
  const void* x      = d_in[0];
  const void* style  = d_in[1];
  const void* weight = d_in[2];
  const void* mod_w  = d_in[3];
  const void* mod_b  = d_in[4];
  char* ws = (char*)d_ws;
  int* flag           = (int*)ws;                                     // 4 B
  float* s_buf        = (float*)(ws + 1024);                          // 16 KB
  unsigned short* Aw  = (unsigned short*)(ws + 32768);                // 37,748,736 B
  unsigned short* xpd = (unsigned short*)(ws + 32768 + 37748736);     // 35,684,352 B

  k_detect   <<<1, 256, 0, stream>>>((const unsigned short*)x, flag);
  k_style    <<<NB, 256, 0, stream>>>(style, mod_w, mod_b, flag, s_buf);
  k_weights  <<<dim3(COUT, NB), 256, 0, stream>>>(weight, s_buf, flag, Aw);
  k_transpose<<<dim3(66, NB), 256, 0, stream>>>(x, flag, xpd);
  k_gemm     <<<512, 512, 0, stream>>>(Aw, xpd, flag, d_out);
}